// Round 16
// baseline (238.747 us; speedup 1.0000x reference)
//
#include <hip/hip_runtime.h>
#include <hip/hip_bf16.h>
#include <stdint.h>

#define S 2048
#define HID 2048
#define NH 16
#define HD 128

typedef short short8 __attribute__((ext_vector_type(8)));
typedef float f32x4 __attribute__((ext_vector_type(4)));
typedef float f32x16 __attribute__((ext_vector_type(16)));
typedef uint32_t u32;
typedef u32 u32x4 __attribute__((ext_vector_type(4)));

__device__ __forceinline__ ushort f2bf(float x) {
  uint32_t u = __builtin_bit_cast(uint32_t, x);
  if ((u & 0x7fffffffu) > 0x7f800000u) return (ushort)((u >> 16) | 0x40);  // quiet NaN
  uint32_t r = u + 0x7fffu + ((u >> 16) & 1u);                             // RNE
  return (ushort)(r >> 16);
}
__device__ __forceinline__ float bf2f(ushort u) {
  union { uint32_t i; float f; } c; c.i = ((uint32_t)u) << 16; return c.f;
}

// async global->LDS, 16B per lane; LDS dest must be wave-uniform (HW adds lane*16)
__device__ __forceinline__ void glds16(const ushort* g, ushort* l) {
  __builtin_amdgcn_global_load_lds((const __attribute__((address_space(1))) uint32_t*)g,
                                   (__attribute__((address_space(3))) uint32_t*)l, 16, 0, 0);
}

// MFMA via inline asm (compiler can't pad MFMA->VALU hazards itself).
__device__ __forceinline__ void mfma16(f32x4& d, short8 a, short8 b) {
  asm volatile("v_mfma_f32_16x16x32_bf16 %0, %1, %2, %0" : "+v"(d) : "v"(a), "v"(b));
}
// 32x32x16 bf16: A row=lane&31,k=(lane>>5)*8+j; B col=lane&31,same k;
// D col=lane&31, row=(reg&3)+8*(reg>>2)+4*(lane>>5)
__device__ __forceinline__ void mfma32(f32x16& d, short8 a, short8 b) {
  asm volatile("v_mfma_f32_32x32x16_bf16 %0, %1, %2, %0" : "+v"(d) : "v"(a), "v"(b));
}
// zero-accumulator start: C = inline constant 0
__device__ __forceinline__ f32x16 mfma32_z(short8 a, short8 b) {
  f32x16 d;
  asm volatile("v_mfma_f32_32x32x16_bf16 %0, %1, %2, 0" : "=v"(d) : "v"(a), "v"(b));
  return d;
}
#define MFMA_FENCE() do {                              \
    asm volatile("s_nop 7\n\ts_nop 7\n\ts_nop 7");     \
    __builtin_amdgcn_sched_barrier(0);                 \
  } while (0)
#define RAW_BARRIER() asm volatile("s_barrier" ::: "memory")
#define SCHED_FENCE() __builtin_amdgcn_sched_barrier(0)
#define MAX3(a, b, c) fmaxf(fmaxf((a), (b)), (c))
__device__ __forceinline__ void plswap(u32& a, u32& b) {
  asm volatile("v_permlane32_swap_b32 %0, %1" : "+v"(a), "+v"(b));
}
__device__ __forceinline__ u32 cvtpk(float lo, float hi) {
  u32 r; asm volatile("v_cvt_pk_bf16_f32 %0, %1, %2" : "=v"(r) : "v"(lo), "v"(hi)); return r;
}

struct CastArgs { const float* s[6]; ushort* d[6]; };
__global__ __launch_bounds__(256) void cast6_k(CastArgs a) {
  const float* in = a.s[blockIdx.y];
  ushort* out = a.d[blockIdx.y];
  int i = blockIdx.x * 256 + threadIdx.x;
  float4 v = ((const float4*)in)[i];
  ushort4 o;
  o.x = f2bf(v.x); o.y = f2bf(v.y); o.z = f2bf(v.z); o.w = f2bf(v.w);
  ((ushort4*)out)[i] = o;
}

// ---------------- 256x256-tile GEMM, m201-style phase schedule -------------
// 8 waves (wr in {0,1}: 128-row half; wc in {0..3}: 64-col strip), BK=64,
// double-buffered LDS 128KB. Per K-tile: stage next tile's 8 glds at phase 0
// (max HBM cover), then 4 phases, each {ds_read quadrant -> barrier ->
// lgkmcnt(0)+sched_fence (rule 18) -> setprio(1) + 16 mfma + setprio(0) ->
// barrier}; one vmcnt(0) drain at the tile boundary (covered by ~4 phases).
// T2 swizzle already conflict-free; T3 phases + T5 setprio per m218/m224.
template <int OUTF32, int NSPLIT>
__device__ __forceinline__ void gemm256_body(const ushort* __restrict__ A,
                                             const ushort* __restrict__ B,
                                             void* __restrict__ C, int N, int K,
                                             long m0, long n0,
                                             ushort* ldsA, ushort* ldsB) {
  const int tid = threadIdx.x, lane = tid & 63, wid = tid >> 6;
  const int g = lane >> 4, c = lane & 15;
  const int wr = wid >> 2, wc = wid & 3;
  const int srow = lane >> 3, sslot = lane & 7;

  f32x4 acc[8][4] = {};

#define GSTAGE256(BO, K0) do {                                                \
    _Pragma("unroll")                                                         \
    for (int i_ = 0; i_ < 4; ++i_) {                                          \
      int ii = wid * 4 + i_;                                                  \
      int rt = ii * 8 + srow;                                                 \
      int col = ((sslot ^ (rt & 7)) << 3) + (K0);                             \
      glds16(A + (m0 + rt) * (long)K + col, ldsA + (BO) * 16384 + ii * 512);  \
      glds16(B + (n0 + rt) * (long)K + col, ldsB + (BO) * 16384 + ii * 512);  \
    } } while (0)

// one phase: read af quadrant (MB = 0 or 4), optionally refresh bfr (RB), MFMA
#define PHASE(LA, LB, KK, MB, RB) do {                                        \
    _Pragma("unroll")                                                         \
    for (int m = 0; m < 4; ++m) {                                             \
      int row = wr * 128 + ((MB) + m) * 16 + c;                               \
      af[m] = *(const short8*)((LA) + row * 64 + ((((KK)*4 + g) ^ (row & 7)) << 3)); \
    }                                                                         \
    if (RB) {                                                                 \
      _Pragma("unroll")                                                       \
      for (int n = 0; n < 4; ++n) {                                           \
        int row = wc * 64 + n * 16 + c;                                       \
        bfr[n] = *(const short8*)((LB) + row * 64 + ((((KK)*4 + g) ^ (row & 7)) << 3)); \
      }                                                                       \
    }                                                                         \
    RAW_BARRIER();                                                            \
    asm volatile("s_waitcnt lgkmcnt(0)");                                     \
    SCHED_FENCE();                                                            \
    __builtin_amdgcn_s_setprio(1);                                            \
    _Pragma("unroll")                                                         \
    for (int m = 0; m < 4; ++m)                                               \
      _Pragma("unroll")                                                       \
      for (int n = 0; n < 4; ++n) mfma16(acc[(MB) + m][n], af[m], bfr[n]);    \
    __builtin_amdgcn_s_setprio(0);                                            \
  } while (0)

  GSTAGE256(0, 0);
  asm volatile("s_waitcnt vmcnt(0)");
  RAW_BARRIER();

#pragma clang loop unroll(disable)
  for (int k0 = 0; k0 < K; k0 += 64) {
    const int bo = (k0 >> 6) & 1;
    const ushort* la = ldsA + bo * 16384;
    const ushort* lb = ldsB + bo * 16384;
    // stage next K-tile into the other buffer (its readers all finished
    // before the previous boundary barrier); dummy wrap on last step
    GSTAGE256(bo ^ 1, (k0 + 64 < K) ? (k0 + 64) : 0);
    SCHED_FENCE();

    short8 af[4], bfr[4];
    PHASE(la, lb, 0, 0, 1);   // P0: m0-3, kk0 (+bfr kk0)
    RAW_BARRIER();
    PHASE(la, lb, 0, 4, 0);   // P1: m4-7, kk0 (bfr reused)
    RAW_BARRIER();
    PHASE(la, lb, 1, 0, 1);   // P2: m0-3, kk1 (+bfr kk1)
    RAW_BARRIER();
    PHASE(la, lb, 1, 4, 0);   // P3: m4-7, kk1
    // tile boundary: next tile's loads (issued at P0, ~4 phases of cover)
    asm volatile("s_waitcnt vmcnt(0)");
    SCHED_FENCE();
    RAW_BARRIER();
  }
#undef PHASE
#undef GSTAGE256
  MFMA_FENCE();
#pragma unroll
  for (int m = 0; m < 8; ++m) {
#pragma unroll
    for (int r = 0; r < 4; ++r) {
      long grow = m0 + wr * 128 + m * 16 + g * 4 + r;
#pragma unroll
      for (int n = 0; n < 4; ++n) {
        long gcol = n0 + wc * 64 + n * 16 + c;
        long idx;
        if (NSPLIT) idx = ((gcol >> 11) << 22) + (grow << 11) + (gcol & 2047);
        else        idx = grow * N + gcol;
        float v = acc[m][n][r];
        if (OUTF32) ((float*)C)[idx] = bf2f(f2bf(v));
        else        ((ushort*)C)[idx] = f2bf(v);
      }
    }
  }
}

// Fused QKV projections: 256 blocks = exactly 1 block/CU.
__global__ __launch_bounds__(512)
void gemm_qkv256_k(const ushort* __restrict__ xs, const ushort* __restrict__ Wq,
                   ushort* __restrict__ q, const ushort* __restrict__ Wkv,
                   ushort* __restrict__ kv) {
  __shared__ __align__(16) ushort ldsA[2 * 256 * 64];
  __shared__ __align__(16) ushort ldsB[2 * 256 * 64];
  const int bid = blockIdx.x;
  if (bid < 128) {
    gemm256_body<0, 0>(xs, Wq, q, 2048, 2048,
                       (long)(bid >> 3) * 256, (long)(bid & 7) * 256, ldsA, ldsB);
  } else {
    const int b2 = bid - 128;
    gemm256_body<0, 1>(xs, Wkv, kv, 4096, 2048,
                       (long)(b2 >> 4) * 256, (long)(b2 & 15) * 256, ldsA, ldsB);
  }
}

// Final projection: validated 128²-tile form, 512 blocks -> 2 blocks/CU
// (2-block desync fills barrier stalls; measured faster than 256x128 1/CU).
template <int OUTF32, int NSPLIT>
__global__ __launch_bounds__(256)
void gemm_bt_k(const ushort* __restrict__ A, const ushort* __restrict__ B,
               void* __restrict__ C, int M, int N, int K) {
  __shared__ __align__(16) ushort ldsA[128 * 64];
  __shared__ __align__(16) ushort ldsB[128 * 64];
  const int tid = threadIdx.x, lane = tid & 63, wid = tid >> 6;
  const int g = lane >> 4, c = lane & 15;
  const int wr = wid >> 1, wc = wid & 1;
  const long m0 = (long)blockIdx.y * 128, n0 = (long)blockIdx.x * 128;
  const int srow = lane >> 3, sslot = lane & 7;

  f32x4 acc[4][4] = {};

  for (int k0 = 0; k0 < K; k0 += 64) {
#pragma unroll
    for (int i = 0; i < 4; ++i) {
      int ii = wid * 4 + i;
      int rt = ii * 8 + srow;
      int col = ((sslot ^ (rt & 7)) << 3) + k0;
      glds16(A + (m0 + rt) * (long)K + col, ldsA + ii * 512);
      glds16(B + (n0 + rt) * (long)K + col, ldsB + ii * 512);
    }
    __syncthreads();
#pragma unroll
    for (int kk = 0; kk < 2; ++kk) {
      short8 af[4], bfr[4];
#pragma unroll
      for (int m = 0; m < 4; ++m) {
        int row = wr * 64 + m * 16 + c;
        af[m] = *(const short8*)(ldsA + row * 64 + (((kk * 4 + g) ^ (row & 7)) << 3));
      }
#pragma unroll
      for (int n = 0; n < 4; ++n) {
        int row = wc * 64 + n * 16 + c;
        bfr[n] = *(const short8*)(ldsB + row * 64 + (((kk * 4 + g) ^ (row & 7)) << 3));
      }
#pragma unroll
      for (int m = 0; m < 4; ++m)
#pragma unroll
        for (int n = 0; n < 4; ++n) mfma16(acc[m][n], af[m], bfr[n]);
    }
    __syncthreads();
  }
  MFMA_FENCE();
#pragma unroll
  for (int m = 0; m < 4; ++m) {
#pragma unroll
    for (int r = 0; r < 4; ++r) {
      long grow = m0 + wr * 64 + m * 16 + g * 4 + r;
#pragma unroll
      for (int n = 0; n < 4; ++n) {
        long gcol = n0 + wc * 64 + n * 16 + c;
        long idx;
        if (NSPLIT) idx = ((gcol >> 11) << 22) + (grow << 11) + (gcol & 2047);
        else        idx = grow * N + gcol;
        float v = acc[m][n][r];
        if (OUTF32) ((float*)C)[idx] = bf2f(f2bf(v));
        else        ((ushort*)C)[idx] = f2bf(v);
      }
    }
  }
}

__global__ __launch_bounds__(256)
void transpose_bf16_k(const ushort* __restrict__ in, ushort* __restrict__ out) {
  __shared__ __align__(16) ushort t[64][72];
  const int tid = threadIdx.x;
  const long bx = (long)blockIdx.x * 64;
  const long by = (long)blockIdx.y * 64;
#pragma unroll
  for (int i = 0; i < 2; ++i) {
    int row = (tid >> 3) + i * 32;
    int col = (tid & 7) * 8;
    *(short8*)(&t[row][col]) = *(const short8*)(in + (by + row) * 2048 + bx + col);
  }
  __syncthreads();
#pragma unroll
  for (int i = 0; i < 2; ++i) {
    int orow = (tid >> 3) + i * 32;
    int ocol = (tid & 7) * 8;
    short8 v;
#pragma unroll
    for (int j = 0; j < 8; ++j) v[j] = (short)t[ocol + j][orow];
    *(short8*)(out + (bx + orow) * 2048 + by + ocol) = v;
  }
}

// mask [q][kv] f32 -> maskQ [kv/4][q][4] bf16 (quad-packed transpose) + nonzero flag.
__global__ __launch_bounds__(256)
void maskQ_k(const float* __restrict__ in, ushort* __restrict__ out,
             u32* __restrict__ flag) {
  __shared__ ushort t[64][72];   // t[kv_local][q_local]
  const int tid = threadIdx.x;
  const long q0 = (long)blockIdx.y * 64;
  const long k0 = (long)blockIdx.x * 64;
  bool nz = false;
#pragma unroll
  for (int i = 0; i < 4; ++i) {
    int row = i * 16 + (tid >> 4);   // q local
    int col = (tid & 15) * 4;        // kv local
    float4 v = *(const float4*)(in + (q0 + row) * S + k0 + col);
    nz = nz || (v.x != 0.f) || (v.y != 0.f) || (v.z != 0.f) || (v.w != 0.f);
    t[col + 0][row] = f2bf(v.x);
    t[col + 1][row] = f2bf(v.y);
    t[col + 2][row] = f2bf(v.z);
    t[col + 3][row] = f2bf(v.w);
  }
  if (__any(nz) && (tid & 63) == 0) atomicOr(flag, 1u);
  __syncthreads();
#pragma unroll
  for (int i = 0; i < 4; ++i) {
    int r4 = i * 4 + (tid >> 6);     // quad row 0..15
    int q = tid & 63;                // q local
    ushort4 o;
    o.x = t[r4 * 4 + 0][q];
    o.y = t[r4 * 4 + 1][q];
    o.z = t[r4 * 4 + 2][q];
    o.w = t[r4 * 4 + 3][q];
    *(ushort4*)(out + ((k0 >> 2) + r4) * (S * 4) + (q0 + q) * 4) = o;
  }
}

// Flash attention: KVBLK=64, 4-wave blocks, 2 blocks/CU, XCD-aware head decode,
// counted-vmcnt + raw-barrier pipeline, kk-outer PV, MFMA C=0 score init.
// Zero-mask fast path (flag==0): skips mask loads + mask VALU, folds SC into
// the exp (max commutes with positive scale), vmcnt(8); mask path vmcnt(16).
// Grid 512, block 256 = 4 waves x 32 q.
__global__ __launch_bounds__(256)
void attn7_k(const ushort* __restrict__ Qself, const ushort* __restrict__ Qcross,
             const ushort* __restrict__ Kp, const ushort* __restrict__ Vt,
             const ushort* __restrict__ maskQ, const u32* __restrict__ flag,
             ushort* __restrict__ outf) {
  __shared__ __align__(16) ushort ldsK[2 * 64 * 128];   // [buf][kv][d], slot^=(row&15)
  __shared__ __align__(16) ushort ldsV[2 * 128 * 64];   // [buf][d][kv], slot^=(row&7)
  const int tid = threadIdx.x, lane = tid & 63, wid = tid >> 6;
  const int c31 = lane & 31, hi = lane >> 5;

  const int b = blockIdx.x;
  const int xcd = b & 7, j = b >> 3;
  const int h = xcd + 8 * (j & 1);
  const int blk = (j >> 1) & 1;       // 0=self 1=cross
  const int qt = j >> 2;              // q-tile of 128 rows

  const ushort* Qp = blk ? Qcross : Qself;
  const int qbase = qt * 128 + wid * 32;
  const long qme = qbase + c31;       // this lane's q-row (owns P row q=c31)

  short8 qf[8];
#pragma unroll
  for (int ks = 0; ks < 8; ++ks)
    qf[ks] = *(const short8*)(Qp + qme * HID + h * HD + ks * 16 + hi * 8);

  f32x16 o[4] = {};   // O[q=(r&3)+8*(r>>2)+4*hi][d = dt*32 + c31]
  float m_r = -__builtin_inff(), l_r = 0.f;

  const float SC  = 0.08838834764831845f;   // 1/sqrt(128)
  const float L2E = 1.4426950408889634f;
  const float SCL = SC * L2E;               // fused scale*log2e (nomask path)
  const float THR = 5.545177444479562f;     // 8*ln2 -> P <= 2^8

  const int kRow4 = lane >> 4, kSlot = lane & 15;
  const int vRow8 = lane >> 3, vSlot = lane & 7;
  const ushort* mqp = maskQ + qme * 4 + hi * (S * 4);
  const int nomask = (*flag == 0);   // wave-uniform

#define STAGE(BO, KV0) do {                                                       \
    _Pragma("unroll")                                                             \
    for (int i_ = 0; i_ < 4; ++i_) {                                              \
      int seg = i_ * 4 + wid;                                                     \
      int rk = seg * 4 + kRow4;                                                   \
      glds16(Kp + (long)((KV0) + rk) * HID + h * HD + ((kSlot ^ (rk & 15)) << 3), \
             ldsK + (BO) * 8192 + seg * 512);                                     \
      int rv = seg * 8 + vRow8;                                                   \
      glds16(Vt + (long)(h * HD + rv) * S + (KV0) + ((vSlot ^ (rv & 7)) << 3),    \
             ldsV + (BO) * 8192 + seg * 512);                                     \
    }                                                                             \
  } while (0)

#define ABODY(T, WM, VMSTR) do {                                                  \
    const int bo = (T) & 1;                                                       \
    const ushort* kb = ldsK + bo * 8192;                                          \
    const ushort* vb = ldsV + bo * 8192;                                          \
    ushort4 mq4[8];                                                               \
    if (WM) {                                                                     \
      _Pragma("unroll")                                                           \
      for (int jj = 0; jj < 8; ++jj)                                              \
        mq4[jj] = *(const ushort4*)(mqp + ((jj & 3) * 2 + (jj >> 2) * 8) * (S * 4)); \
      SCHED_FENCE();                                                              \
    }                                                                             \
    STAGE(bo ^ 1, (((T) + 1) & 31) * 64);                                         \
    SCHED_FENCE();                                                                \
    asm volatile(VMSTR);                                                          \
    SCHED_FENCE();                                                                \
    RAW_BARRIER();                                                                \
    f32x16 s0, s1;                                                                \
    __builtin_amdgcn_s_setprio(1);                                                \
    {                                                                             \
      const int r0 = c31, r1 = 32 + c31;                                          \
      short8 kf0 = *(const short8*)(kb + r0 * 128 + ((hi ^ (r0 & 15)) << 3));     \
      short8 kf1 = *(const short8*)(kb + r1 * 128 + ((hi ^ (r1 & 15)) << 3));     \
      s0 = mfma32_z(kf0, qf[0]);                                                  \
      s1 = mfma32_z(kf1, qf[0]);                                                  \
    }                                                                             \
    _Pragma("unroll")                                                             \
    for (int ks = 1; ks < 8; ++ks) {                                              \
      int r0 = c31, r1 = 32 + c31;                                                \
      short8 kf0 = *(const short8*)(kb + r0 * 128 + (((ks * 2 + hi) ^ (r0 & 15)) << 3)); \
      short8 kf1 = *(const short8*)(kb + r1 * 128 + (((ks * 2 + hi) ^ (r1 & 15)) << 3)); \
      mfma32(s0, kf0, qf[ks]);                                                    \
      mfma32(s1, kf1, qf[ks]);                                                    \
    }                                                                             \
    __builtin_amdgcn_s_setprio(0);                                                \
    MFMA_FENCE();                                                                 \
    if (WM) {                                                                     \
      _Pragma("unroll")                                                           \
      for (int r = 0; r < 16; ++r) {                                              \
        s0[r] = __builtin_fmaf(s0[r], SC, bf2f(mq4[r >> 2][r & 3]));              \
        s1[r] = __builtin_fmaf(s1[r], SC, bf2f(mq4[4 + (r >> 2)][r & 3]));        \
      }                                                                           \
    }                                                                             \
    float a0 = MAX3(s0[0], s0[1], s0[2]);                                         \
    float a1 = MAX3(s0[3], s0[4], s0[5]);                                         \
    float a2 = MAX3(s0[6], s0[7], s0[8]);                                         \
    float a3 = MAX3(s0[9], s0[10], s0[11]);                                       \
    float a4 = MAX3(s0[12], s0[13], s0[14]);                                      \
    float a5 = MAX3(s0[15], s1[0], s1[1]);                                        \
    float a6 = MAX3(s1[2], s1[3], s1[4]);                                         \
    float a7 = MAX3(s1[5], s1[6], s1[7]);                                         \
    float a8 = MAX3(s1[8], s1[9], s1[10]);                                        \
    float a9 = MAX3(s1[11], s1[12], s1[13]);                                      \
    float a10 = fmaxf(s1[14], s1[15]);                                            \
    float b0 = MAX3(a0, a1, a2);                                                  \
    float b1 = MAX3(a3, a4, a5);                                                  \
    float b2 = MAX3(a6, a7, a8);                                                  \
    float b3 = fmaxf(a9, a10);                                                    \
    float pm = MAX3(b0, b1, fmaxf(b2, b3));                                       \
    float pmax = fmaxf(pm, __shfl_xor(pm, 32));                                   \
    if (!WM) pmax *= SC;   /* max commutes with positive scale */                 \
    if (!__all(pmax <= m_r + THR)) {                                              \
      float mnew = fmaxf(m_r, pmax);                                              \
      float alpha = __builtin_amdgcn_exp2f((m_r - mnew) * L2E);                   \
      m_r = mnew;                                                                 \
      l_r *= alpha;                                                               \
      _Pragma("unroll")                                                           \
      for (int r = 0; r < 16; ++r) {                                              \
        float alf = __shfl(alpha, (r & 3) + 8 * (r >> 2) + 4 * hi);               \
        _Pragma("unroll")                                                         \
        for (int dt = 0; dt < 4; ++dt) o[dt][r] *= alf;                           \
      }                                                                           \
    }                                                                             \
    const float nm = -m_r * L2E;                                                  \
    const float el = WM ? L2E : SCL;                                              \
    _Pragma("unroll")                                                             \
    for (int r = 0; r < 16; ++r) {                                                \
      s0[r] = __builtin_amdgcn_exp2f(__builtin_fmaf(s0[r], el, nm));              \
      s1[r] = __builtin_amdgcn_exp2f(__builtin_fmaf(s1[r], el, nm));              \
    }                                                                             \
    float sm[16];                                                                 \
    _Pragma("unroll")                                                             \
    for (int r = 0; r < 16; ++r) sm[r] = s0[r] + s1[r];                           \
    _Pragma("unroll")                                                             \
    for (int st = 8; st >= 1; st >>= 1)                                           \
      _Pragma("unroll")                                                           \
      for (int i = 0; i < 8; ++i)                                                 \
        if (i < st) sm[i] += sm[i + st];                                          \
    l_r += sm[0] + __shfl_xor(sm[0], 32);                                         \
    short8 pa[4];                                                                 \
    _Pragma("unroll")                                                             \
    for (int kk = 0; kk < 4; ++kk) {                                              \
      const f32x16& sv = (kk < 2) ? s0 : s1;                                      \
      const int bq = (kk & 1) * 8;                                                \
      u32 x0 = cvtpk(sv[bq + 0], sv[bq + 1]);                                     \
      u32 x1 = cvtpk(sv[bq + 2], sv[bq + 3]);                                     \
      u32 y0 = cvtpk(sv[bq + 4], sv[bq + 5]);                                     \
      u32 y1 = cvtpk(sv[bq + 6], sv[bq + 7]);                                     \
      plswap(x0, y0);                                                             \
      plswap(x1, y1);                                                             \
      u32x4 tt; tt[0] = x0; tt[1] = x1; tt[2] = y0; tt[3] = y1;                   \
      pa[kk] = __builtin_bit_cast(short8, tt);                                    \
    }                                                                             \
    asm volatile("s_nop 1");                                                      \
    SCHED_FENCE();                                                                \
    __builtin_amdgcn_s_setprio(1);                                                \
    _Pragma("unroll")                                                             \
    for (int kk = 0; kk < 4; ++kk) {                                              \
      _Pragma("unroll")                                                           \
      for (int dt = 0; dt < 4; ++dt) {                                            \
        int row = dt * 32 + c31;                                                  \
        short8 vf = *(const short8*)(vb + row * 64 + (((kk * 2 + hi) ^ (row & 7)) << 3)); \
        mfma32(o[dt], pa[kk], vf);                                                \
      }                                                                           \
    }                                                                             \
    __builtin_amdgcn_s_setprio(0);                                                \
    RAW_BARRIER();                                                                \
    if (WM) mqp += 16 * (S * 4);                                                  \
  } while (0)

  STAGE(0, 0);  // prologue: 8 loads outstanding

  if (nomask) {
#pragma clang loop unroll(disable)
    for (int t = 0; t < 32; ++t) { ABODY(t, 0, "s_waitcnt vmcnt(8)"); }
  } else {
#pragma clang loop unroll(disable)
    for (int t = 0; t < 32; ++t) { ABODY(t, 1, "s_waitcnt vmcnt(16)"); }
  }
#undef ABODY
#undef STAGE

  MFMA_FENCE();  // o[] read by VALU epilogue
#pragma unroll
  for (int r = 0; r < 16; ++r) {
    int qr = (r & 3) + 8 * (r >> 2) + 4 * hi;
    float linv = 1.0f / __shfl(l_r, qr);
    long orow = 2L * (qbase + qr) + blk;
#pragma unroll
    for (int dt = 0; dt < 4; ++dt)
      outf[orow * HID + h * HD + dt * 32 + c31] = f2bf(o[dt][r] * linv);
  }
}

extern "C" void kernel_launch(void* const* d_in, const int* in_sizes, int n_in,
                              void* d_out, int out_size, void* d_ws, size_t ws_size,
                              hipStream_t stream) {
  (void)in_sizes; (void)n_in; (void)out_size; (void)ws_size;
  const float* x_self  = (const float*)d_in[0];
  const float* x_cross = (const float*)d_in[1];
  const float* mask    = (const float*)d_in[2];
  const float* Wq      = (const float*)d_in[3];
  const float* Wk      = (const float*)d_in[4];
  const float* Wv      = (const float*)d_in[5];
  const float* Wo      = (const float*)d_in[6];

  uint8_t* w = (uint8_t*)d_ws;
  const size_t MB8 = (size_t)S * HID * sizeof(ushort);  // 8 MiB
  ushort* xs_bf   = (ushort*)(w + 0 * MB8);  // later reused as Vt
  ushort* xc_bf   = (ushort*)(w + 1 * MB8);  // later reused as mask flag
  ushort* Wq_bf   = (ushort*)(w + 2 * MB8);  // later reused as out_flat (16MB w/ Wk)
  ushort* Wk_bf   = (ushort*)(w + 3 * MB8);  // contiguous with Wv_bf -> [Wk|Wv]
  ushort* Wv_bf   = (ushort*)(w + 4 * MB8);
  ushort* Wo_bf   = (ushort*)(w + 5 * MB8);
  ushort* q_self  = (ushort*)(w + 6 * MB8);  // contiguous with q_cross
  ushort* q_cross = (ushort*)(w + 7 * MB8);
  ushort* k_      = (ushort*)(w + 8 * MB8);  // contiguous with v_
  ushort* v_      = (ushort*)(w + 9 * MB8);
  ushort* vt       = xs_bf;          // alias: xs/xc dead after projections
  ushort* out_flat = Wq_bf;          // alias: Wq/Wk bf16 dead after projections
  ushort* maskQ    = v_;             // alias: v_ dead after V-transpose
  u32*    mflag    = (u32*)xc_bf;    // alias: xc dead after projections

  CastArgs ca;
  ca.s[0] = x_self;  ca.d[0] = xs_bf;
  ca.s[1] = x_cross; ca.d[1] = xc_bf;
  ca.s[2] = Wq;      ca.d[2] = Wq_bf;
  ca.s[3] = Wk;      ca.d[3] = Wk_bf;
  ca.s[4] = Wv;      ca.d[4] = Wv_bf;
  ca.s[5] = Wo;      ca.d[5] = Wo_bf;
  cast6_k<<<dim3(4096, 6), 256, 0, stream>>>(ca);

  // fused QKV projections: 256 blocks of 512 threads = 1 block/CU chip-wide
  gemm_qkv256_k<<<dim3(256), 512, 0, stream>>>(xs_bf, Wq_bf, q_self, Wk_bf, k_);

  transpose_bf16_k<<<dim3(32, 32), 256, 0, stream>>>(v_, vt);
  hipMemsetAsync(mflag, 0, 4, stream);
  maskQ_k<<<dim3(32, 32), 256, 0, stream>>>(mask, maskQ, mflag);  // after v_ consumed

  attn7_k<<<dim3(512), 256, 0, stream>>>(q_self, q_cross, k_, vt, maskQ, mflag, out_flat);

  // out = f32(bf16(out_flat @ Wo^T))  — validated 128² form, 2 blocks/CU
  gemm_bt_k<1, 0><<<dim3(16, 32), 256, 0, stream>>>(out_flat, Wo_bf, d_out, 4096, 2048, 2048);
}

// Round 17
// 225.267 us; speedup vs baseline: 1.0598x; 1.0598x over previous
//
#include <hip/hip_runtime.h>
#include <hip/hip_bf16.h>
#include <stdint.h>

#define S 2048
#define HID 2048
#define NH 16
#define HD 128

typedef short short8 __attribute__((ext_vector_type(8)));
typedef float f32x4 __attribute__((ext_vector_type(4)));
typedef float f32x16 __attribute__((ext_vector_type(16)));
typedef uint32_t u32;
typedef u32 u32x4 __attribute__((ext_vector_type(4)));

__device__ __forceinline__ ushort f2bf(float x) {
  uint32_t u = __builtin_bit_cast(uint32_t, x);
  if ((u & 0x7fffffffu) > 0x7f800000u) return (ushort)((u >> 16) | 0x40);  // quiet NaN
  uint32_t r = u + 0x7fffu + ((u >> 16) & 1u);                             // RNE
  return (ushort)(r >> 16);
}
__device__ __forceinline__ float bf2f(ushort u) {
  union { uint32_t i; float f; } c; c.i = ((uint32_t)u) << 16; return c.f;
}

// async global->LDS, 16B per lane; LDS dest must be wave-uniform (HW adds lane*16)
__device__ __forceinline__ void glds16(const ushort* g, ushort* l) {
  __builtin_amdgcn_global_load_lds((const __attribute__((address_space(1))) uint32_t*)g,
                                   (__attribute__((address_space(3))) uint32_t*)l, 16, 0, 0);
}

// MFMA via inline asm (compiler can't pad MFMA->VALU hazards itself).
__device__ __forceinline__ void mfma16(f32x4& d, short8 a, short8 b) {
  asm volatile("v_mfma_f32_16x16x32_bf16 %0, %1, %2, %0" : "+v"(d) : "v"(a), "v"(b));
}
// 32x32x16 bf16: A row=lane&31,k=(lane>>5)*8+j; B col=lane&31,same k;
// D col=lane&31, row=(reg&3)+8*(reg>>2)+4*(lane>>5)
__device__ __forceinline__ void mfma32(f32x16& d, short8 a, short8 b) {
  asm volatile("v_mfma_f32_32x32x16_bf16 %0, %1, %2, %0" : "+v"(d) : "v"(a), "v"(b));
}
// zero-accumulator start: C = inline constant 0
__device__ __forceinline__ f32x16 mfma32_z(short8 a, short8 b) {
  f32x16 d;
  asm volatile("v_mfma_f32_32x32x16_bf16 %0, %1, %2, 0" : "=v"(d) : "v"(a), "v"(b));
  return d;
}
#define MFMA_FENCE() do {                              \
    asm volatile("s_nop 7\n\ts_nop 7\n\ts_nop 7");     \
    __builtin_amdgcn_sched_barrier(0);                 \
  } while (0)
#define RAW_BARRIER() asm volatile("s_barrier" ::: "memory")
#define SCHED_FENCE() __builtin_amdgcn_sched_barrier(0)
#define MAX3(a, b, c) fmaxf(fmaxf((a), (b)), (c))
__device__ __forceinline__ void plswap(u32& a, u32& b) {
  asm volatile("v_permlane32_swap_b32 %0, %1" : "+v"(a), "+v"(b));
}
__device__ __forceinline__ u32 cvtpk(float lo, float hi) {
  u32 r; asm volatile("v_cvt_pk_bf16_f32 %0, %1, %2" : "=v"(r) : "v"(lo), "v"(hi)); return r;
}

struct CastArgs { const float* s[6]; ushort* d[6]; };
__global__ __launch_bounds__(256) void cast6_k(CastArgs a) {
  const float* in = a.s[blockIdx.y];
  ushort* out = a.d[blockIdx.y];
  int i = blockIdx.x * 256 + threadIdx.x;
  float4 v = ((const float4*)in)[i];
  ushort4 o;
  o.x = f2bf(v.x); o.y = f2bf(v.y); o.z = f2bf(v.z); o.w = f2bf(v.w);
  ((ushort4*)out)[i] = o;
}

// ---------------- 256x256-tile GEMM (8 waves, BK=64, dbuf + counted vmcnt) ----
// Validated round-13 schedule: stage next tile (8 glds) -> vmcnt(8) (pops
// exactly THIS tile's 8; next tile's stay in flight) -> raw barrier ->
// 24 ds_read + 64 mfma16/wave -> raw barrier. Counted-vmcnt, 2 barriers/tile.
// Phase-split variants regressed at 2 waves/SIMD (rounds 9, 14, 16): fewer
// barriers win when there aren't enough waves to fill phase boundaries.
template <int OUTF32, int NSPLIT>
__device__ __forceinline__ void gemm256_body(const ushort* __restrict__ A,
                                             const ushort* __restrict__ B,
                                             void* __restrict__ C, int N, int K,
                                             long m0, long n0,
                                             ushort* ldsA, ushort* ldsB) {
  const int tid = threadIdx.x, lane = tid & 63, wid = tid >> 6;
  const int g = lane >> 4, c = lane & 15;
  const int wr = wid >> 2, wc = wid & 3;
  const int srow = lane >> 3, sslot = lane & 7;

  f32x4 acc[8][4] = {};

#define GSTAGE256(BO, K0) do {                                                \
    _Pragma("unroll")                                                         \
    for (int i_ = 0; i_ < 4; ++i_) {                                          \
      int ii = wid * 4 + i_;                                                  \
      int rt = ii * 8 + srow;                                                 \
      int col = ((sslot ^ (rt & 7)) << 3) + (K0);                             \
      glds16(A + (m0 + rt) * (long)K + col, ldsA + (BO) * 16384 + ii * 512);  \
      glds16(B + (n0 + rt) * (long)K + col, ldsB + (BO) * 16384 + ii * 512);  \
    } } while (0)

  GSTAGE256(0, 0);

#pragma clang loop unroll(disable)
  for (int k0 = 0; k0 < K; k0 += 64) {
    const int bo = (k0 >> 6) & 1;
    GSTAGE256(bo ^ 1, (k0 + 64 < K) ? (k0 + 64) : 0);
    SCHED_FENCE();
    asm volatile("s_waitcnt vmcnt(8)");
    SCHED_FENCE();
    RAW_BARRIER();
    const ushort* la = ldsA + bo * 16384;
    const ushort* lb = ldsB + bo * 16384;
#pragma unroll
    for (int kk = 0; kk < 2; ++kk) {
      short8 af[8], bfr[4];
#pragma unroll
      for (int m = 0; m < 8; ++m) {
        int row = wr * 128 + m * 16 + c;
        af[m] = *(const short8*)(la + row * 64 + (((kk * 4 + g) ^ (row & 7)) << 3));
      }
#pragma unroll
      for (int n = 0; n < 4; ++n) {
        int row = wc * 64 + n * 16 + c;
        bfr[n] = *(const short8*)(lb + row * 64 + (((kk * 4 + g) ^ (row & 7)) << 3));
      }
#pragma unroll
      for (int m = 0; m < 8; ++m)
#pragma unroll
        for (int n = 0; n < 4; ++n) mfma16(acc[m][n], af[m], bfr[n]);
    }
    RAW_BARRIER();
  }
#undef GSTAGE256
  MFMA_FENCE();
#pragma unroll
  for (int m = 0; m < 8; ++m) {
#pragma unroll
    for (int r = 0; r < 4; ++r) {
      long grow = m0 + wr * 128 + m * 16 + g * 4 + r;
#pragma unroll
      for (int n = 0; n < 4; ++n) {
        long gcol = n0 + wc * 64 + n * 16 + c;
        long idx;
        if (NSPLIT) idx = ((gcol >> 11) << 22) + (grow << 11) + (gcol & 2047);
        else        idx = grow * N + gcol;
        float v = acc[m][n][r];
        if (OUTF32) ((float*)C)[idx] = bf2f(f2bf(v));
        else        ((ushort*)C)[idx] = f2bf(v);
      }
    }
  }
}

// Fused QKV projections: 256 blocks = exactly 1 block/CU.
__global__ __launch_bounds__(512)
void gemm_qkv256_k(const ushort* __restrict__ xs, const ushort* __restrict__ Wq,
                   ushort* __restrict__ q, const ushort* __restrict__ Wkv,
                   ushort* __restrict__ kv) {
  __shared__ __align__(16) ushort ldsA[2 * 256 * 64];
  __shared__ __align__(16) ushort ldsB[2 * 256 * 64];
  const int bid = blockIdx.x;
  if (bid < 128) {
    gemm256_body<0, 0>(xs, Wq, q, 2048, 2048,
                       (long)(bid >> 3) * 256, (long)(bid & 7) * 256, ldsA, ldsB);
  } else {
    const int b2 = bid - 128;
    gemm256_body<0, 1>(xs, Wkv, kv, 4096, 2048,
                       (long)(b2 >> 4) * 256, (long)(b2 & 15) * 256, ldsA, ldsB);
  }
}

// Final projection: validated 128²-tile form, 512 blocks -> 2 blocks/CU
// (2-block desync fills barrier stalls; measured faster than 256x128 1/CU).
template <int OUTF32, int NSPLIT>
__global__ __launch_bounds__(256)
void gemm_bt_k(const ushort* __restrict__ A, const ushort* __restrict__ B,
               void* __restrict__ C, int M, int N, int K) {
  __shared__ __align__(16) ushort ldsA[128 * 64];
  __shared__ __align__(16) ushort ldsB[128 * 64];
  const int tid = threadIdx.x, lane = tid & 63, wid = tid >> 6;
  const int g = lane >> 4, c = lane & 15;
  const int wr = wid >> 1, wc = wid & 1;
  const long m0 = (long)blockIdx.y * 128, n0 = (long)blockIdx.x * 128;
  const int srow = lane >> 3, sslot = lane & 7;

  f32x4 acc[4][4] = {};

  for (int k0 = 0; k0 < K; k0 += 64) {
#pragma unroll
    for (int i = 0; i < 4; ++i) {
      int ii = wid * 4 + i;
      int rt = ii * 8 + srow;
      int col = ((sslot ^ (rt & 7)) << 3) + k0;
      glds16(A + (m0 + rt) * (long)K + col, ldsA + ii * 512);
      glds16(B + (n0 + rt) * (long)K + col, ldsB + ii * 512);
    }
    __syncthreads();
#pragma unroll
    for (int kk = 0; kk < 2; ++kk) {
      short8 af[4], bfr[4];
#pragma unroll
      for (int m = 0; m < 4; ++m) {
        int row = wr * 64 + m * 16 + c;
        af[m] = *(const short8*)(ldsA + row * 64 + (((kk * 4 + g) ^ (row & 7)) << 3));
      }
#pragma unroll
      for (int n = 0; n < 4; ++n) {
        int row = wc * 64 + n * 16 + c;
        bfr[n] = *(const short8*)(ldsB + row * 64 + (((kk * 4 + g) ^ (row & 7)) << 3));
      }
#pragma unroll
      for (int m = 0; m < 4; ++m)
#pragma unroll
        for (int n = 0; n < 4; ++n) mfma16(acc[m][n], af[m], bfr[n]);
    }
    __syncthreads();
  }
  MFMA_FENCE();
#pragma unroll
  for (int m = 0; m < 4; ++m) {
#pragma unroll
    for (int r = 0; r < 4; ++r) {
      long grow = m0 + wr * 64 + m * 16 + g * 4 + r;
#pragma unroll
      for (int n = 0; n < 4; ++n) {
        long gcol = n0 + wc * 64 + n * 16 + c;
        long idx;
        if (NSPLIT) idx = ((gcol >> 11) << 22) + (grow << 11) + (gcol & 2047);
        else        idx = grow * N + gcol;
        float v = acc[m][n][r];
        if (OUTF32) ((float*)C)[idx] = bf2f(f2bf(v));
        else        ((ushort*)C)[idx] = f2bf(v);
      }
    }
  }
}

// Fused prep: blocks 0..1023 transpose v_ -> vt; blocks 1024..2047 build
// quad-packed maskQ + nonzero flag. One launch instead of two.
__global__ __launch_bounds__(256)
void prep_k(const ushort* __restrict__ vin, ushort* __restrict__ vout,
            const float* __restrict__ min_, ushort* __restrict__ mout,
            u32* __restrict__ flag) {
  __shared__ __align__(16) ushort t[64][72];
  const int tid = threadIdx.x;
  const int bid = blockIdx.x;
  if (bid < 1024) {
    const long bx = (long)(bid & 31) * 64;
    const long by = (long)(bid >> 5) * 64;
#pragma unroll
    for (int i = 0; i < 2; ++i) {
      int row = (tid >> 3) + i * 32;
      int col = (tid & 7) * 8;
      *(short8*)(&t[row][col]) = *(const short8*)(vin + (by + row) * 2048 + bx + col);
    }
    __syncthreads();
#pragma unroll
    for (int i = 0; i < 2; ++i) {
      int orow = (tid >> 3) + i * 32;
      int ocol = (tid & 7) * 8;
      short8 v;
#pragma unroll
      for (int j = 0; j < 8; ++j) v[j] = (short)t[ocol + j][orow];
      *(short8*)(vout + (bx + orow) * 2048 + by + ocol) = v;
    }
  } else {
    const int b2 = bid - 1024;
    const long q0 = (long)(b2 >> 5) * 64;
    const long k0 = (long)(b2 & 31) * 64;
    bool nz = false;
#pragma unroll
    for (int i = 0; i < 4; ++i) {
      int row = i * 16 + (tid >> 4);   // q local
      int col = (tid & 15) * 4;        // kv local
      float4 v = *(const float4*)(min_ + (q0 + row) * S + k0 + col);
      nz = nz || (v.x != 0.f) || (v.y != 0.f) || (v.z != 0.f) || (v.w != 0.f);
      t[col + 0][row] = f2bf(v.x);
      t[col + 1][row] = f2bf(v.y);
      t[col + 2][row] = f2bf(v.z);
      t[col + 3][row] = f2bf(v.w);
    }
    if (__any(nz) && (tid & 63) == 0) atomicOr(flag, 1u);
    __syncthreads();
#pragma unroll
    for (int i = 0; i < 4; ++i) {
      int r4 = i * 4 + (tid >> 6);     // quad row 0..15
      int q = tid & 63;                // q local
      ushort4 o;
      o.x = t[r4 * 4 + 0][q];
      o.y = t[r4 * 4 + 1][q];
      o.z = t[r4 * 4 + 2][q];
      o.w = t[r4 * 4 + 3][q];
      *(ushort4*)(mout + ((k0 >> 2) + r4) * (S * 4) + (q0 + q) * 4) = o;
    }
  }
}

// Flash attention: KVBLK=64, 4-wave blocks, 2 blocks/CU, XCD-aware head decode,
// counted-vmcnt + raw-barrier pipeline, kk-outer PV, MFMA C=0 score init.
// Zero-mask fast path (flag==0): skips mask loads + mask VALU, folds SC into
// the exp (max commutes with positive scale), vmcnt(8); mask path vmcnt(16).
// Grid 512, block 256 = 4 waves x 32 q.
__global__ __launch_bounds__(256)
void attn7_k(const ushort* __restrict__ Qself, const ushort* __restrict__ Qcross,
             const ushort* __restrict__ Kp, const ushort* __restrict__ Vt,
             const ushort* __restrict__ maskQ, const u32* __restrict__ flag,
             ushort* __restrict__ outf) {
  __shared__ __align__(16) ushort ldsK[2 * 64 * 128];   // [buf][kv][d], slot^=(row&15)
  __shared__ __align__(16) ushort ldsV[2 * 128 * 64];   // [buf][d][kv], slot^=(row&7)
  const int tid = threadIdx.x, lane = tid & 63, wid = tid >> 6;
  const int c31 = lane & 31, hi = lane >> 5;

  const int b = blockIdx.x;
  const int xcd = b & 7, j = b >> 3;
  const int h = xcd + 8 * (j & 1);
  const int blk = (j >> 1) & 1;       // 0=self 1=cross
  const int qt = j >> 2;              // q-tile of 128 rows

  const ushort* Qp = blk ? Qcross : Qself;
  const int qbase = qt * 128 + wid * 32;
  const long qme = qbase + c31;       // this lane's q-row (owns P row q=c31)

  short8 qf[8];
#pragma unroll
  for (int ks = 0; ks < 8; ++ks)
    qf[ks] = *(const short8*)(Qp + qme * HID + h * HD + ks * 16 + hi * 8);

  f32x16 o[4] = {};   // O[q=(r&3)+8*(r>>2)+4*hi][d = dt*32 + c31]
  float m_r = -__builtin_inff(), l_r = 0.f;

  const float SC  = 0.08838834764831845f;   // 1/sqrt(128)
  const float L2E = 1.4426950408889634f;
  const float SCL = SC * L2E;               // fused scale*log2e (nomask path)
  const float THR = 5.545177444479562f;     // 8*ln2 -> P <= 2^8

  const int kRow4 = lane >> 4, kSlot = lane & 15;
  const int vRow8 = lane >> 3, vSlot = lane & 7;
  const ushort* mqp = maskQ + qme * 4 + hi * (S * 4);
  const int nomask = (*flag == 0);   // wave-uniform

#define STAGE(BO, KV0) do {                                                       \
    _Pragma("unroll")                                                             \
    for (int i_ = 0; i_ < 4; ++i_) {                                              \
      int seg = i_ * 4 + wid;                                                     \
      int rk = seg * 4 + kRow4;                                                   \
      glds16(Kp + (long)((KV0) + rk) * HID + h * HD + ((kSlot ^ (rk & 15)) << 3), \
             ldsK + (BO) * 8192 + seg * 512);                                     \
      int rv = seg * 8 + vRow8;                                                   \
      glds16(Vt + (long)(h * HD + rv) * S + (KV0) + ((vSlot ^ (rv & 7)) << 3),    \
             ldsV + (BO) * 8192 + seg * 512);                                     \
    }                                                                             \
  } while (0)

#define ABODY(T, WM, VMSTR) do {                                                  \
    const int bo = (T) & 1;                                                       \
    const ushort* kb = ldsK + bo * 8192;                                          \
    const ushort* vb = ldsV + bo * 8192;                                          \
    ushort4 mq4[8];                                                               \
    if (WM) {                                                                     \
      _Pragma("unroll")                                                           \
      for (int jj = 0; jj < 8; ++jj)                                              \
        mq4[jj] = *(const ushort4*)(mqp + ((jj & 3) * 2 + (jj >> 2) * 8) * (S * 4)); \
      SCHED_FENCE();                                                              \
    }                                                                             \
    STAGE(bo ^ 1, (((T) + 1) & 31) * 64);                                         \
    SCHED_FENCE();                                                                \
    asm volatile(VMSTR);                                                          \
    SCHED_FENCE();                                                                \
    RAW_BARRIER();                                                                \
    f32x16 s0, s1;                                                                \
    __builtin_amdgcn_s_setprio(1);                                                \
    {                                                                             \
      const int r0 = c31, r1 = 32 + c31;                                          \
      short8 kf0 = *(const short8*)(kb + r0 * 128 + ((hi ^ (r0 & 15)) << 3));     \
      short8 kf1 = *(const short8*)(kb + r1 * 128 + ((hi ^ (r1 & 15)) << 3));     \
      s0 = mfma32_z(kf0, qf[0]);                                                  \
      s1 = mfma32_z(kf1, qf[0]);                                                  \
    }                                                                             \
    _Pragma("unroll")                                                             \
    for (int ks = 1; ks < 8; ++ks) {                                              \
      int r0 = c31, r1 = 32 + c31;                                                \
      short8 kf0 = *(const short8*)(kb + r0 * 128 + (((ks * 2 + hi) ^ (r0 & 15)) << 3)); \
      short8 kf1 = *(const short8*)(kb + r1 * 128 + (((ks * 2 + hi) ^ (r1 & 15)) << 3)); \
      mfma32(s0, kf0, qf[ks]);                                                    \
      mfma32(s1, kf1, qf[ks]);                                                    \
    }                                                                             \
    __builtin_amdgcn_s_setprio(0);                                                \
    MFMA_FENCE();                                                                 \
    if (WM) {                                                                     \
      _Pragma("unroll")                                                           \
      for (int r = 0; r < 16; ++r) {                                              \
        s0[r] = __builtin_fmaf(s0[r], SC, bf2f(mq4[r >> 2][r & 3]));              \
        s1[r] = __builtin_fmaf(s1[r], SC, bf2f(mq4[4 + (r >> 2)][r & 3]));        \
      }                                                                           \
    }                                                                             \
    float a0 = MAX3(s0[0], s0[1], s0[2]);                                         \
    float a1 = MAX3(s0[3], s0[4], s0[5]);                                         \
    float a2 = MAX3(s0[6], s0[7], s0[8]);                                         \
    float a3 = MAX3(s0[9], s0[10], s0[11]);                                       \
    float a4 = MAX3(s0[12], s0[13], s0[14]);                                      \
    float a5 = MAX3(s0[15], s1[0], s1[1]);                                        \
    float a6 = MAX3(s1[2], s1[3], s1[4]);                                         \
    float a7 = MAX3(s1[5], s1[6], s1[7]);                                         \
    float a8 = MAX3(s1[8], s1[9], s1[10]);                                        \
    float a9 = MAX3(s1[11], s1[12], s1[13]);                                      \
    float a10 = fmaxf(s1[14], s1[15]);                                            \
    float b0 = MAX3(a0, a1, a2);                                                  \
    float b1 = MAX3(a3, a4, a5);                                                  \
    float b2 = MAX3(a6, a7, a8);                                                  \
    float b3 = fmaxf(a9, a10);                                                    \
    float pm = MAX3(b0, b1, fmaxf(b2, b3));                                       \
    float pmax = fmaxf(pm, __shfl_xor(pm, 32));                                   \
    if (!WM) pmax *= SC;   /* max commutes with positive scale */                 \
    if (!__all(pmax <= m_r + THR)) {                                              \
      float mnew = fmaxf(m_r, pmax);                                              \
      float alpha = __builtin_amdgcn_exp2f((m_r - mnew) * L2E);                   \
      m_r = mnew;                                                                 \
      l_r *= alpha;                                                               \
      _Pragma("unroll")                                                           \
      for (int r = 0; r < 16; ++r) {                                              \
        float alf = __shfl(alpha, (r & 3) + 8 * (r >> 2) + 4 * hi);               \
        _Pragma("unroll")                                                         \
        for (int dt = 0; dt < 4; ++dt) o[dt][r] *= alf;                           \
      }                                                                           \
    }                                                                             \
    const float nm = -m_r * L2E;                                                  \
    const float el = WM ? L2E : SCL;                                              \
    _Pragma("unroll")                                                             \
    for (int r = 0; r < 16; ++r) {                                                \
      s0[r] = __builtin_amdgcn_exp2f(__builtin_fmaf(s0[r], el, nm));              \
      s1[r] = __builtin_amdgcn_exp2f(__builtin_fmaf(s1[r], el, nm));              \
    }                                                                             \
    float sm[16];                                                                 \
    _Pragma("unroll")                                                             \
    for (int r = 0; r < 16; ++r) sm[r] = s0[r] + s1[r];                           \
    _Pragma("unroll")                                                             \
    for (int st = 8; st >= 1; st >>= 1)                                           \
      _Pragma("unroll")                                                           \
      for (int i = 0; i < 8; ++i)                                                 \
        if (i < st) sm[i] += sm[i + st];                                          \
    l_r += sm[0] + __shfl_xor(sm[0], 32);                                         \
    short8 pa[4];                                                                 \
    _Pragma("unroll")                                                             \
    for (int kk = 0; kk < 4; ++kk) {                                              \
      const f32x16& sv = (kk < 2) ? s0 : s1;                                      \
      const int bq = (kk & 1) * 8;                                                \
      u32 x0 = cvtpk(sv[bq + 0], sv[bq + 1]);                                     \
      u32 x1 = cvtpk(sv[bq + 2], sv[bq + 3]);                                     \
      u32 y0 = cvtpk(sv[bq + 4], sv[bq + 5]);                                     \
      u32 y1 = cvtpk(sv[bq + 6], sv[bq + 7]);                                     \
      plswap(x0, y0);                                                             \
      plswap(x1, y1);                                                             \
      u32x4 tt; tt[0] = x0; tt[1] = x1; tt[2] = y0; tt[3] = y1;                   \
      pa[kk] = __builtin_bit_cast(short8, tt);                                    \
    }                                                                             \
    asm volatile("s_nop 1");                                                      \
    SCHED_FENCE();                                                                \
    __builtin_amdgcn_s_setprio(1);                                                \
    _Pragma("unroll")                                                             \
    for (int kk = 0; kk < 4; ++kk) {                                              \
      _Pragma("unroll")                                                           \
      for (int dt = 0; dt < 4; ++dt) {                                            \
        int row = dt * 32 + c31;                                                  \
        short8 vf = *(const short8*)(vb + row * 64 + (((kk * 2 + hi) ^ (row & 7)) << 3)); \
        mfma32(o[dt], pa[kk], vf);                                                \
      }                                                                           \
    }                                                                             \
    __builtin_amdgcn_s_setprio(0);                                                \
    RAW_BARRIER();                                                                \
    if (WM) mqp += 16 * (S * 4);                                                  \
  } while (0)

  STAGE(0, 0);  // prologue: 8 loads outstanding

  if (nomask) {
#pragma clang loop unroll(disable)
    for (int t = 0; t < 32; ++t) { ABODY(t, 0, "s_waitcnt vmcnt(8)"); }
  } else {
#pragma clang loop unroll(disable)
    for (int t = 0; t < 32; ++t) { ABODY(t, 1, "s_waitcnt vmcnt(16)"); }
  }
#undef ABODY
#undef STAGE

  MFMA_FENCE();  // o[] read by VALU epilogue
#pragma unroll
  for (int r = 0; r < 16; ++r) {
    int qr = (r & 3) + 8 * (r >> 2) + 4 * hi;
    float linv = 1.0f / __shfl(l_r, qr);
    long orow = 2L * (qbase + qr) + blk;
#pragma unroll
    for (int dt = 0; dt < 4; ++dt)
      outf[orow * HID + h * HD + dt * 32 + c31] = f2bf(o[dt][r] * linv);
  }
}

extern "C" void kernel_launch(void* const* d_in, const int* in_sizes, int n_in,
                              void* d_out, int out_size, void* d_ws, size_t ws_size,
                              hipStream_t stream) {
  (void)in_sizes; (void)n_in; (void)out_size; (void)ws_size;
  const float* x_self  = (const float*)d_in[0];
  const float* x_cross = (const float*)d_in[1];
  const float* mask    = (const float*)d_in[2];
  const float* Wq      = (const float*)d_in[3];
  const float* Wk      = (const float*)d_in[4];
  const float* Wv      = (const float*)d_in[5];
  const float* Wo      = (const float*)d_in[6];

  uint8_t* w = (uint8_t*)d_ws;
  const size_t MB8 = (size_t)S * HID * sizeof(ushort);  // 8 MiB
  ushort* xs_bf   = (ushort*)(w + 0 * MB8);  // later reused as Vt
  ushort* xc_bf   = (ushort*)(w + 1 * MB8);  // later reused as mask flag
  ushort* Wq_bf   = (ushort*)(w + 2 * MB8);  // later reused as out_flat (16MB w/ Wk)
  ushort* Wk_bf   = (ushort*)(w + 3 * MB8);  // contiguous with Wv_bf -> [Wk|Wv]
  ushort* Wv_bf   = (ushort*)(w + 4 * MB8);
  ushort* Wo_bf   = (ushort*)(w + 5 * MB8);
  ushort* q_self  = (ushort*)(w + 6 * MB8);  // contiguous with q_cross
  ushort* q_cross = (ushort*)(w + 7 * MB8);
  ushort* k_      = (ushort*)(w + 8 * MB8);  // contiguous with v_
  ushort* v_      = (ushort*)(w + 9 * MB8);
  ushort* vt       = xs_bf;          // alias: xs/xc dead after projections
  ushort* out_flat = Wq_bf;          // alias: Wq/Wk bf16 dead after projections
  ushort* maskQ    = v_;             // alias: v_ dead after V-transpose
  u32*    mflag    = (u32*)xc_bf;    // alias: xc dead after projections

  CastArgs ca;
  ca.s[0] = x_self;  ca.d[0] = xs_bf;
  ca.s[1] = x_cross; ca.d[1] = xc_bf;
  ca.s[2] = Wq;      ca.d[2] = Wq_bf;
  ca.s[3] = Wk;      ca.d[3] = Wk_bf;
  ca.s[4] = Wv;      ca.d[4] = Wv_bf;
  ca.s[5] = Wo;      ca.d[5] = Wo_bf;
  cast6_k<<<dim3(4096, 6), 256, 0, stream>>>(ca);

  // fused QKV projections: 256 blocks of 512 threads = 1 block/CU chip-wide
  gemm_qkv256_k<<<dim3(256), 512, 0, stream>>>(xs_bf, Wq_bf, q_self, Wk_bf, k_);

  hipMemsetAsync(mflag, 0, 4, stream);
  // fused prep: V-transpose (1024 blocks) + maskQ build (1024 blocks)
  prep_k<<<dim3(2048), 256, 0, stream>>>(v_, vt, mask, maskQ, mflag);

  attn7_k<<<dim3(512), 256, 0, stream>>>(q_self, q_cross, k_, vt, maskQ, mflag, out_flat);

  // out = f32(bf16(out_flat @ Wo^T))  — validated 128² form, 2 blocks/CU
  gemm_bt_k<1, 0><<<dim3(16, 32), 256, 0, stream>>>(out_flat, Wo_bf, d_out, 4096, 2048, 2048);
}

// Round 18
// 224.650 us; speedup vs baseline: 1.0628x; 1.0027x over previous
//
#include <hip/hip_runtime.h>
#include <hip/hip_bf16.h>
#include <stdint.h>

#define S 2048
#define HID 2048
#define NH 16
#define HD 128

typedef short short8 __attribute__((ext_vector_type(8)));
typedef float f32x4 __attribute__((ext_vector_type(4)));
typedef float f32x16 __attribute__((ext_vector_type(16)));
typedef uint32_t u32;
typedef u32 u32x4 __attribute__((ext_vector_type(4)));

__device__ __forceinline__ ushort f2bf(float x) {
  uint32_t u = __builtin_bit_cast(uint32_t, x);
  if ((u & 0x7fffffffu) > 0x7f800000u) return (ushort)((u >> 16) | 0x40);  // quiet NaN
  uint32_t r = u + 0x7fffu + ((u >> 16) & 1u);                             // RNE
  return (ushort)(r >> 16);
}
__device__ __forceinline__ float bf2f(ushort u) {
  union { uint32_t i; float f; } c; c.i = ((uint32_t)u) << 16; return c.f;
}

// async global->LDS, 16B per lane; LDS dest must be wave-uniform (HW adds lane*16)
__device__ __forceinline__ void glds16(const ushort* g, ushort* l) {
  __builtin_amdgcn_global_load_lds((const __attribute__((address_space(1))) uint32_t*)g,
                                   (__attribute__((address_space(3))) uint32_t*)l, 16, 0, 0);
}

// MFMA via inline asm (compiler can't pad MFMA->VALU hazards itself).
__device__ __forceinline__ void mfma16(f32x4& d, short8 a, short8 b) {
  asm volatile("v_mfma_f32_16x16x32_bf16 %0, %1, %2, %0" : "+v"(d) : "v"(a), "v"(b));
}
// 32x32x16 bf16: A row=lane&31,k=(lane>>5)*8+j; B col=lane&31,same k;
// D col=lane&31, row=(reg&3)+8*(reg>>2)+4*(lane>>5)
__device__ __forceinline__ void mfma32(f32x16& d, short8 a, short8 b) {
  asm volatile("v_mfma_f32_32x32x16_bf16 %0, %1, %2, %0" : "+v"(d) : "v"(a), "v"(b));
}
// zero-accumulator start: C = inline constant 0
__device__ __forceinline__ f32x16 mfma32_z(short8 a, short8 b) {
  f32x16 d;
  asm volatile("v_mfma_f32_32x32x16_bf16 %0, %1, %2, 0" : "=v"(d) : "v"(a), "v"(b));
  return d;
}
#define MFMA_FENCE() do {                              \
    asm volatile("s_nop 7\n\ts_nop 7\n\ts_nop 7");     \
    __builtin_amdgcn_sched_barrier(0);                 \
  } while (0)
#define RAW_BARRIER() asm volatile("s_barrier" ::: "memory")
#define SCHED_FENCE() __builtin_amdgcn_sched_barrier(0)
#define MAX3(a, b, c) fmaxf(fmaxf((a), (b)), (c))
__device__ __forceinline__ void plswap(u32& a, u32& b) {
  asm volatile("v_permlane32_swap_b32 %0, %1" : "+v"(a), "+v"(b));
}
__device__ __forceinline__ u32 cvtpk(float lo, float hi) {
  u32 r; asm volatile("v_cvt_pk_bf16_f32 %0, %1, %2" : "=v"(r) : "v"(lo), "v"(hi)); return r;
}

struct CastArgs { const float* s[6]; ushort* d[6]; };
__global__ __launch_bounds__(256) void cast6_k(CastArgs a) {
  const float* in = a.s[blockIdx.y];
  ushort* out = a.d[blockIdx.y];
  int i = blockIdx.x * 256 + threadIdx.x;
  float4 v = ((const float4*)in)[i];
  ushort4 o;
  o.x = f2bf(v.x); o.y = f2bf(v.y); o.z = f2bf(v.z); o.w = f2bf(v.w);
  ((ushort4*)out)[i] = o;
}

// ---------------- 256x256-tile GEMM (8 waves, BK=64, dbuf + counted vmcnt) ----
// Validated round-13 schedule: stage next tile (8 glds) -> vmcnt(8) -> raw
// barrier -> 24 ds_read + 64 mfma16/wave -> raw barrier. 2 barriers/tile.
// Phase-split variants regressed at 2 waves/SIMD (rounds 9, 14, 16).
template <int OUTF32, int NSPLIT>
__device__ __forceinline__ void gemm256_body(const ushort* __restrict__ A,
                                             const ushort* __restrict__ B,
                                             void* __restrict__ C, int N, int K,
                                             long m0, long n0,
                                             ushort* ldsA, ushort* ldsB) {
  const int tid = threadIdx.x, lane = tid & 63, wid = tid >> 6;
  const int g = lane >> 4, c = lane & 15;
  const int wr = wid >> 2, wc = wid & 3;
  const int srow = lane >> 3, sslot = lane & 7;

  f32x4 acc[8][4] = {};

#define GSTAGE256(BO, K0) do {                                                \
    _Pragma("unroll")                                                         \
    for (int i_ = 0; i_ < 4; ++i_) {                                          \
      int ii = wid * 4 + i_;                                                  \
      int rt = ii * 8 + srow;                                                 \
      int col = ((sslot ^ (rt & 7)) << 3) + (K0);                             \
      glds16(A + (m0 + rt) * (long)K + col, ldsA + (BO) * 16384 + ii * 512);  \
      glds16(B + (n0 + rt) * (long)K + col, ldsB + (BO) * 16384 + ii * 512);  \
    } } while (0)

  GSTAGE256(0, 0);

#pragma clang loop unroll(disable)
  for (int k0 = 0; k0 < K; k0 += 64) {
    const int bo = (k0 >> 6) & 1;
    GSTAGE256(bo ^ 1, (k0 + 64 < K) ? (k0 + 64) : 0);
    SCHED_FENCE();
    asm volatile("s_waitcnt vmcnt(8)");
    SCHED_FENCE();
    RAW_BARRIER();
    const ushort* la = ldsA + bo * 16384;
    const ushort* lb = ldsB + bo * 16384;
#pragma unroll
    for (int kk = 0; kk < 2; ++kk) {
      short8 af[8], bfr[4];
#pragma unroll
      for (int m = 0; m < 8; ++m) {
        int row = wr * 128 + m * 16 + c;
        af[m] = *(const short8*)(la + row * 64 + (((kk * 4 + g) ^ (row & 7)) << 3));
      }
#pragma unroll
      for (int n = 0; n < 4; ++n) {
        int row = wc * 64 + n * 16 + c;
        bfr[n] = *(const short8*)(lb + row * 64 + (((kk * 4 + g) ^ (row & 7)) << 3));
      }
#pragma unroll
      for (int m = 0; m < 8; ++m)
#pragma unroll
        for (int n = 0; n < 4; ++n) mfma16(acc[m][n], af[m], bfr[n]);
    }
    RAW_BARRIER();
  }
#undef GSTAGE256
  MFMA_FENCE();
#pragma unroll
  for (int m = 0; m < 8; ++m) {
#pragma unroll
    for (int r = 0; r < 4; ++r) {
      long grow = m0 + wr * 128 + m * 16 + g * 4 + r;
#pragma unroll
      for (int n = 0; n < 4; ++n) {
        long gcol = n0 + wc * 64 + n * 16 + c;
        long idx;
        if (NSPLIT) idx = ((gcol >> 11) << 22) + (grow << 11) + (gcol & 2047);
        else        idx = grow * N + gcol;
        float v = acc[m][n][r];
        if (OUTF32) ((float*)C)[idx] = bf2f(f2bf(v));
        else        ((ushort*)C)[idx] = f2bf(v);
      }
    }
  }
}

// Fused QKV projections: 256 blocks = exactly 1 block/CU.
__global__ __launch_bounds__(512)
void gemm_qkv256_k(const ushort* __restrict__ xs, const ushort* __restrict__ Wq,
                   ushort* __restrict__ q, const ushort* __restrict__ Wkv,
                   ushort* __restrict__ kv) {
  __shared__ __align__(16) ushort ldsA[2 * 256 * 64];
  __shared__ __align__(16) ushort ldsB[2 * 256 * 64];
  const int bid = blockIdx.x;
  if (bid < 128) {
    gemm256_body<0, 0>(xs, Wq, q, 2048, 2048,
                       (long)(bid >> 3) * 256, (long)(bid & 7) * 256, ldsA, ldsB);
  } else {
    const int b2 = bid - 128;
    gemm256_body<0, 1>(xs, Wkv, kv, 4096, 2048,
                       (long)(b2 >> 4) * 256, (long)(b2 & 15) * 256, ldsA, ldsB);
  }
}

// Final projection: validated 128²-tile form, 512 blocks -> 2 blocks/CU.
template <int OUTF32, int NSPLIT>
__global__ __launch_bounds__(256)
void gemm_bt_k(const ushort* __restrict__ A, const ushort* __restrict__ B,
               void* __restrict__ C, int M, int N, int K) {
  __shared__ __align__(16) ushort ldsA[128 * 64];
  __shared__ __align__(16) ushort ldsB[128 * 64];
  const int tid = threadIdx.x, lane = tid & 63, wid = tid >> 6;
  const int g = lane >> 4, c = lane & 15;
  const int wr = wid >> 1, wc = wid & 1;
  const long m0 = (long)blockIdx.y * 128, n0 = (long)blockIdx.x * 128;
  const int srow = lane >> 3, sslot = lane & 7;

  f32x4 acc[4][4] = {};

  for (int k0 = 0; k0 < K; k0 += 64) {
#pragma unroll
    for (int i = 0; i < 4; ++i) {
      int ii = wid * 4 + i;
      int rt = ii * 8 + srow;
      int col = ((sslot ^ (rt & 7)) << 3) + k0;
      glds16(A + (m0 + rt) * (long)K + col, ldsA + ii * 512);
      glds16(B + (n0 + rt) * (long)K + col, ldsB + ii * 512);
    }
    __syncthreads();
#pragma unroll
    for (int kk = 0; kk < 2; ++kk) {
      short8 af[4], bfr[4];
#pragma unroll
      for (int m = 0; m < 4; ++m) {
        int row = wr * 64 + m * 16 + c;
        af[m] = *(const short8*)(ldsA + row * 64 + (((kk * 4 + g) ^ (row & 7)) << 3));
      }
#pragma unroll
      for (int n = 0; n < 4; ++n) {
        int row = wc * 64 + n * 16 + c;
        bfr[n] = *(const short8*)(ldsB + row * 64 + (((kk * 4 + g) ^ (row & 7)) << 3));
      }
#pragma unroll
      for (int m = 0; m < 4; ++m)
#pragma unroll
        for (int n = 0; n < 4; ++n) mfma16(acc[m][n], af[m], bfr[n]);
    }
    __syncthreads();
  }
  MFMA_FENCE();
#pragma unroll
  for (int m = 0; m < 4; ++m) {
#pragma unroll
    for (int r = 0; r < 4; ++r) {
      long grow = m0 + wr * 64 + m * 16 + g * 4 + r;
#pragma unroll
      for (int n = 0; n < 4; ++n) {
        long gcol = n0 + wc * 64 + n * 16 + c;
        long idx;
        if (NSPLIT) idx = ((gcol >> 11) << 22) + (grow << 11) + (gcol & 2047);
        else        idx = grow * N + gcol;
        float v = acc[m][n][r];
        if (OUTF32) ((float*)C)[idx] = bf2f(f2bf(v));
        else        ((ushort*)C)[idx] = f2bf(v);
      }
    }
  }
}

// Fused prep: blocks 0..1023 transpose v_ -> vt; blocks 1024..2047 build
// quad-packed maskQ + nonzero flag.
__global__ __launch_bounds__(256)
void prep_k(const ushort* __restrict__ vin, ushort* __restrict__ vout,
            const float* __restrict__ min_, ushort* __restrict__ mout,
            u32* __restrict__ flag) {
  __shared__ __align__(16) ushort t[64][72];
  const int tid = threadIdx.x;
  const int bid = blockIdx.x;
  if (bid < 1024) {
    const long bx = (long)(bid & 31) * 64;
    const long by = (long)(bid >> 5) * 64;
#pragma unroll
    for (int i = 0; i < 2; ++i) {
      int row = (tid >> 3) + i * 32;
      int col = (tid & 7) * 8;
      *(short8*)(&t[row][col]) = *(const short8*)(vin + (by + row) * 2048 + bx + col);
    }
    __syncthreads();
#pragma unroll
    for (int i = 0; i < 2; ++i) {
      int orow = (tid >> 3) + i * 32;
      int ocol = (tid & 7) * 8;
      short8 v;
#pragma unroll
      for (int j = 0; j < 8; ++j) v[j] = (short)t[ocol + j][orow];
      *(short8*)(vout + (bx + orow) * 2048 + by + ocol) = v;
    }
  } else {
    const int b2 = bid - 1024;
    const long q0 = (long)(b2 >> 5) * 64;
    const long k0 = (long)(b2 & 31) * 64;
    bool nz = false;
#pragma unroll
    for (int i = 0; i < 4; ++i) {
      int row = i * 16 + (tid >> 4);   // q local
      int col = (tid & 15) * 4;        // kv local
      float4 v = *(const float4*)(min_ + (q0 + row) * S + k0 + col);
      nz = nz || (v.x != 0.f) || (v.y != 0.f) || (v.z != 0.f) || (v.w != 0.f);
      t[col + 0][row] = f2bf(v.x);
      t[col + 1][row] = f2bf(v.y);
      t[col + 2][row] = f2bf(v.z);
      t[col + 3][row] = f2bf(v.w);
    }
    if (__any(nz) && (tid & 63) == 0) atomicOr(flag, 1u);
    __syncthreads();
#pragma unroll
    for (int i = 0; i < 4; ++i) {
      int r4 = i * 4 + (tid >> 6);     // quad row 0..15
      int q = tid & 63;                // q local
      ushort4 o;
      o.x = t[r4 * 4 + 0][q];
      o.y = t[r4 * 4 + 1][q];
      o.z = t[r4 * 4 + 2][q];
      o.w = t[r4 * 4 + 3][q];
      *(ushort4*)(mout + ((k0 >> 2) + r4) * (S * 4) + (q0 + q) * 4) = o;
    }
  }
}

// Flash attention: KVBLK=64, 4-wave blocks, 2 blocks/CU, XCD-aware head decode,
// counted-vmcnt + raw-barrier pipeline, kk-outer PV, MFMA C=0 score init,
// ones-column-MFMA denominator (l lands in O-row layout; removes the lsum
// VALU tree + epilogue shuffles; safe now that MFMA->VALU hazards are fenced).
// Zero-mask fast path (flag==0): vmcnt(8); mask path vmcnt(16).
// Grid 512, block 256 = 4 waves x 32 q.
__global__ __launch_bounds__(256)
void attn7_k(const ushort* __restrict__ Qself, const ushort* __restrict__ Qcross,
             const ushort* __restrict__ Kp, const ushort* __restrict__ Vt,
             const ushort* __restrict__ maskQ, const u32* __restrict__ flag,
             ushort* __restrict__ outf) {
  __shared__ __align__(16) ushort ldsK[2 * 64 * 128];   // [buf][kv][d], slot^=(row&15)
  __shared__ __align__(16) ushort ldsV[2 * 128 * 64];   // [buf][d][kv], slot^=(row&7)
  const int tid = threadIdx.x, lane = tid & 63, wid = tid >> 6;
  const int c31 = lane & 31, hi = lane >> 5;

  const int b = blockIdx.x;
  const int xcd = b & 7, j = b >> 3;
  const int h = xcd + 8 * (j & 1);
  const int blk = (j >> 1) & 1;       // 0=self 1=cross
  const int qt = j >> 2;              // q-tile of 128 rows

  const ushort* Qp = blk ? Qcross : Qself;
  const int qbase = qt * 128 + wid * 32;
  const long qme = qbase + c31;       // this lane's q-row (owns P row q=c31)

  short8 qf[8];
#pragma unroll
  for (int ks = 0; ks < 8; ++ks)
    qf[ks] = *(const short8*)(Qp + qme * HID + h * HD + ks * 16 + hi * 8);

  f32x16 o[4] = {};   // O[q=(r&3)+8*(r>>2)+4*hi][d = dt*32 + c31]
  f32x16 o4 = {};     // denominator: row-sum of bf16 P, same row layout
  float m_r = -__builtin_inff();

  const float SC  = 0.08838834764831845f;   // 1/sqrt(128)
  const float L2E = 1.4426950408889634f;
  const float SCL = SC * L2E;               // fused scale*log2e (nomask path)
  const float THR = 5.545177444479562f;     // 8*ln2 -> P <= 2^8

  const int kRow4 = lane >> 4, kSlot = lane & 15;
  const int vRow8 = lane >> 3, vSlot = lane & 7;
  const ushort* mqp = maskQ + qme * 4 + hi * (S * 4);
  const int nomask = (*flag == 0);   // wave-uniform

  u32x4 onespk; onespk[0] = onespk[1] = onespk[2] = onespk[3] = 0x3f803f80u;
  const short8 ones = __builtin_bit_cast(short8, onespk);

#define STAGE(BO, KV0) do {                                                       \
    _Pragma("unroll")                                                             \
    for (int i_ = 0; i_ < 4; ++i_) {                                              \
      int seg = i_ * 4 + wid;                                                     \
      int rk = seg * 4 + kRow4;                                                   \
      glds16(Kp + (long)((KV0) + rk) * HID + h * HD + ((kSlot ^ (rk & 15)) << 3), \
             ldsK + (BO) * 8192 + seg * 512);                                     \
      int rv = seg * 8 + vRow8;                                                   \
      glds16(Vt + (long)(h * HD + rv) * S + (KV0) + ((vSlot ^ (rv & 7)) << 3),    \
             ldsV + (BO) * 8192 + seg * 512);                                     \
    }                                                                             \
  } while (0)

#define ABODY(T, WM, VMSTR) do {                                                  \
    const int bo = (T) & 1;                                                       \
    const ushort* kb = ldsK + bo * 8192;                                          \
    const ushort* vb = ldsV + bo * 8192;                                          \
    ushort4 mq4[8];                                                               \
    if (WM) {                                                                     \
      _Pragma("unroll")                                                           \
      for (int jj = 0; jj < 8; ++jj)                                              \
        mq4[jj] = *(const ushort4*)(mqp + ((jj & 3) * 2 + (jj >> 2) * 8) * (S * 4)); \
      SCHED_FENCE();                                                              \
    }                                                                             \
    STAGE(bo ^ 1, (((T) + 1) & 31) * 64);                                         \
    SCHED_FENCE();                                                                \
    asm volatile(VMSTR);                                                          \
    SCHED_FENCE();                                                                \
    RAW_BARRIER();                                                                \
    f32x16 s0, s1;                                                                \
    __builtin_amdgcn_s_setprio(1);                                                \
    {                                                                             \
      const int r0 = c31, r1 = 32 + c31;                                          \
      short8 kf0 = *(const short8*)(kb + r0 * 128 + ((hi ^ (r0 & 15)) << 3));     \
      short8 kf1 = *(const short8*)(kb + r1 * 128 + ((hi ^ (r1 & 15)) << 3));     \
      s0 = mfma32_z(kf0, qf[0]);                                                  \
      s1 = mfma32_z(kf1, qf[0]);                                                  \
    }                                                                             \
    _Pragma("unroll")                                                             \
    for (int ks = 1; ks < 8; ++ks) {                                              \
      int r0 = c31, r1 = 32 + c31;                                                \
      short8 kf0 = *(const short8*)(kb + r0 * 128 + (((ks * 2 + hi) ^ (r0 & 15)) << 3)); \
      short8 kf1 = *(const short8*)(kb + r1 * 128 + (((ks * 2 + hi) ^ (r1 & 15)) << 3)); \
      mfma32(s0, kf0, qf[ks]);                                                    \
      mfma32(s1, kf1, qf[ks]);                                                    \
    }                                                                             \
    __builtin_amdgcn_s_setprio(0);                                                \
    MFMA_FENCE();                                                                 \
    if (WM) {                                                                     \
      _Pragma("unroll")                                                           \
      for (int r = 0; r < 16; ++r) {                                              \
        s0[r] = __builtin_fmaf(s0[r], SC, bf2f(mq4[r >> 2][r & 3]));              \
        s1[r] = __builtin_fmaf(s1[r], SC, bf2f(mq4[4 + (r >> 2)][r & 3]));        \
      }                                                                           \
    }                                                                             \
    float a0 = MAX3(s0[0], s0[1], s0[2]);                                         \
    float a1 = MAX3(s0[3], s0[4], s0[5]);                                         \
    float a2 = MAX3(s0[6], s0[7], s0[8]);                                         \
    float a3 = MAX3(s0[9], s0[10], s0[11]);                                       \
    float a4 = MAX3(s0[12], s0[13], s0[14]);                                      \
    float a5 = MAX3(s0[15], s1[0], s1[1]);                                        \
    float a6 = MAX3(s1[2], s1[3], s1[4]);                                         \
    float a7 = MAX3(s1[5], s1[6], s1[7]);                                         \
    float a8 = MAX3(s1[8], s1[9], s1[10]);                                        \
    float a9 = MAX3(s1[11], s1[12], s1[13]);                                      \
    float a10 = fmaxf(s1[14], s1[15]);                                            \
    float b0 = MAX3(a0, a1, a2);                                                  \
    float b1 = MAX3(a3, a4, a5);                                                  \
    float b2 = MAX3(a6, a7, a8);                                                  \
    float b3 = fmaxf(a9, a10);                                                    \
    float pm = MAX3(b0, b1, fmaxf(b2, b3));                                       \
    float pmax = fmaxf(pm, __shfl_xor(pm, 32));                                   \
    if (!WM) pmax *= SC;   /* max commutes with positive scale */                 \
    if (!__all(pmax <= m_r + THR)) {                                              \
      float mnew = fmaxf(m_r, pmax);                                              \
      float alpha = __builtin_amdgcn_exp2f((m_r - mnew) * L2E);                   \
      m_r = mnew;                                                                 \
      _Pragma("unroll")                                                           \
      for (int r = 0; r < 16; ++r) {                                              \
        float alf = __shfl(alpha, (r & 3) + 8 * (r >> 2) + 4 * hi);               \
        _Pragma("unroll")                                                         \
        for (int dt = 0; dt < 4; ++dt) o[dt][r] *= alf;                           \
        o4[r] *= alf;                                                             \
      }                                                                           \
    }                                                                             \
    const float nm = -m_r * L2E;                                                  \
    const float el = WM ? L2E : SCL;                                              \
    _Pragma("unroll")                                                             \
    for (int r = 0; r < 16; ++r) {                                                \
      s0[r] = __builtin_amdgcn_exp2f(__builtin_fmaf(s0[r], el, nm));              \
      s1[r] = __builtin_amdgcn_exp2f(__builtin_fmaf(s1[r], el, nm));              \
    }                                                                             \
    short8 pa[4];                                                                 \
    _Pragma("unroll")                                                             \
    for (int kk = 0; kk < 4; ++kk) {                                              \
      const f32x16& sv = (kk < 2) ? s0 : s1;                                      \
      const int bq = (kk & 1) * 8;                                                \
      u32 x0 = cvtpk(sv[bq + 0], sv[bq + 1]);                                     \
      u32 x1 = cvtpk(sv[bq + 2], sv[bq + 3]);                                     \
      u32 y0 = cvtpk(sv[bq + 4], sv[bq + 5]);                                     \
      u32 y1 = cvtpk(sv[bq + 6], sv[bq + 7]);                                     \
      plswap(x0, y0);                                                             \
      plswap(x1, y1);                                                             \
      u32x4 tt; tt[0] = x0; tt[1] = x1; tt[2] = y0; tt[3] = y1;                   \
      pa[kk] = __builtin_bit_cast(short8, tt);                                    \
    }                                                                             \
    asm volatile("s_nop 1");                                                      \
    SCHED_FENCE();                                                                \
    __builtin_amdgcn_s_setprio(1);                                                \
    _Pragma("unroll")                                                             \
    for (int kk = 0; kk < 4; ++kk) {                                              \
      _Pragma("unroll")                                                           \
      for (int dt = 0; dt < 4; ++dt) {                                            \
        int row = dt * 32 + c31;                                                  \
        short8 vf = *(const short8*)(vb + row * 64 + (((kk * 2 + hi) ^ (row & 7)) << 3)); \
        mfma32(o[dt], pa[kk], vf);                                                \
      }                                                                           \
    }                                                                             \
    _Pragma("unroll")                                                             \
    for (int kk = 0; kk < 4; ++kk) mfma32(o4, pa[kk], ones);                      \
    __builtin_amdgcn_s_setprio(0);                                                \
    RAW_BARRIER();                                                                \
    if (WM) mqp += 16 * (S * 4);                                                  \
  } while (0)

  STAGE(0, 0);  // prologue: 8 loads outstanding

  if (nomask) {
#pragma clang loop unroll(disable)
    for (int t = 0; t < 32; ++t) { ABODY(t, 0, "s_waitcnt vmcnt(8)"); }
  } else {
#pragma clang loop unroll(disable)
    for (int t = 0; t < 32; ++t) { ABODY(t, 1, "s_waitcnt vmcnt(16)"); }
  }
#undef ABODY
#undef STAGE

  MFMA_FENCE();  // o[]/o4 read by VALU epilogue; o4 written by the LAST mfma
#pragma unroll
  for (int r = 0; r < 16; ++r) {
    int qr = (r & 3) + 8 * (r >> 2) + 4 * hi;
    float linv = 1.0f / o4[r];
    long orow = 2L * (qbase + qr) + blk;
#pragma unroll
    for (int dt = 0; dt < 4; ++dt)
      outf[orow * HID + h * HD + dt * 32 + c31] = f2bf(o[dt][r] * linv);
  }
}

extern "C" void kernel_launch(void* const* d_in, const int* in_sizes, int n_in,
                              void* d_out, int out_size, void* d_ws, size_t ws_size,
                              hipStream_t stream) {
  (void)in_sizes; (void)n_in; (void)out_size; (void)ws_size;
  const float* x_self  = (const float*)d_in[0];
  const float* x_cross = (const float*)d_in[1];
  const float* mask    = (const float*)d_in[2];
  const float* Wq      = (const float*)d_in[3];
  const float* Wk      = (const float*)d_in[4];
  const float* Wv      = (const float*)d_in[5];
  const float* Wo      = (const float*)d_in[6];

  uint8_t* w = (uint8_t*)d_ws;
  const size_t MB8 = (size_t)S * HID * sizeof(ushort);  // 8 MiB
  ushort* xs_bf   = (ushort*)(w + 0 * MB8);  // later reused as Vt
  ushort* xc_bf   = (ushort*)(w + 1 * MB8);  // later reused as mask flag
  ushort* Wq_bf   = (ushort*)(w + 2 * MB8);  // later reused as out_flat (16MB w/ Wk)
  ushort* Wk_bf   = (ushort*)(w + 3 * MB8);  // contiguous with Wv_bf -> [Wk|Wv]
  ushort* Wv_bf   = (ushort*)(w + 4 * MB8);
  ushort* Wo_bf   = (ushort*)(w + 5 * MB8);
  ushort* q_self  = (ushort*)(w + 6 * MB8);  // contiguous with q_cross
  ushort* q_cross = (ushort*)(w + 7 * MB8);
  ushort* k_      = (ushort*)(w + 8 * MB8);  // contiguous with v_
  ushort* v_      = (ushort*)(w + 9 * MB8);
  ushort* vt       = xs_bf;          // alias: xs/xc dead after projections
  ushort* out_flat = Wq_bf;          // alias: Wq/Wk bf16 dead after projections
  ushort* maskQ    = v_;             // alias: v_ dead after V-transpose
  u32*    mflag    = (u32*)xc_bf;    // alias: xc dead after projections

  CastArgs ca;
  ca.s[0] = x_self;  ca.d[0] = xs_bf;
  ca.s[1] = x_cross; ca.d[1] = xc_bf;
  ca.s[2] = Wq;      ca.d[2] = Wq_bf;
  ca.s[3] = Wk;      ca.d[3] = Wk_bf;
  ca.s[4] = Wv;      ca.d[4] = Wv_bf;
  ca.s[5] = Wo;      ca.d[5] = Wo_bf;
  cast6_k<<<dim3(4096, 6), 256, 0, stream>>>(ca);

  // fused QKV projections: 256 blocks of 512 threads = 1 block/CU chip-wide
  gemm_qkv256_k<<<dim3(256), 512, 0, stream>>>(xs_bf, Wq_bf, q_self, Wk_bf, k_);

  hipMemsetAsync(mflag, 0, 4, stream);
  // fused prep: V-transpose (1024 blocks) + maskQ build (1024 blocks)
  prep_k<<<dim3(2048), 256, 0, stream>>>(v_, vt, mask, maskQ, mflag);

  attn7_k<<<dim3(512), 256, 0, stream>>>(q_self, q_cross, k_, vt, maskQ, mflag, out_flat);

  // out = f32(bf16(out_flat @ Wo^T))  — validated 128² form, 2 blocks/CU
  gemm_bt_k<1, 0><<<dim3(16, 32), 256, 0, stream>>>(out_flat, Wo_bf, d_out, 4096, 2048, 2048);
}